// Round 4
// baseline (506.259 us; speedup 1.0000x reference)
//
#include <hip/hip_runtime.h>
#include <hip/hip_bf16.h>

// Problem: B=16, S=2048, H=1024
//   a = encoder_outputs (B,S,H) f32
//   projh[b,o] = sum_h h[b,h]*W[o,h] + bias[o]
//   scores[b,s] = sum_o relu( sum_h a[b,s,h]*W[o,H+h] + projh[b,o] ) * v[o]
//   weights = softmax_s(scores); context[b,h] = sum_s weights[b,s]*a[b,s,h]
// Outputs concat: context (16*1024 f32) then weights (16*2048 f32)

typedef __bf16 bf16x8 __attribute__((ext_vector_type(8)));
typedef float floatx4 __attribute__((ext_vector_type(4)));

#define BB 16
#define SS 2048
#define HH 1024
#define MM (BB * SS)

__device__ inline ushort f2bf(float x) {
    uint32_t u = __builtin_bit_cast(uint32_t, x);
    u += 0x7FFFu + ((u >> 16) & 1u);   // round-to-nearest-even
    return (ushort)(u >> 16);
}

// ---------------- f32 -> bf16 bulk convert (A: 33.5M elems) ----------------
__global__ __launch_bounds__(256) void convert_A_kernel(
    const float* __restrict__ src, __bf16* __restrict__ dst)
{
    size_t i = (size_t)blockIdx.x * 256 + threadIdx.x;   // 8-elem group
    const float* s = src + i * 8;
    float4 a = *(const float4*)(s);
    float4 b = *(const float4*)(s + 4);
    union { ushort u[8]; uint4 v; } p;
    p.u[0] = f2bf(a.x); p.u[1] = f2bf(a.y); p.u[2] = f2bf(a.z); p.u[3] = f2bf(a.w);
    p.u[4] = f2bf(b.x); p.u[5] = f2bf(b.y); p.u[6] = f2bf(b.z); p.u[7] = f2bf(b.w);
    *(uint4*)(dst + i * 8) = p.v;
}

// ---------------- prep: projh (blocks 0..255) + convert_W (256..319) + zero (320..335) ----
__global__ __launch_bounds__(256) void prep_kernel(
    const float* __restrict__ h, const float* __restrict__ W,
    const float* __restrict__ bias, float* __restrict__ projh,
    __bf16* __restrict__ Wb, float* __restrict__ scores, float* __restrict__ ctx)
{
    int bid = blockIdx.x;
    int tid = threadIdx.x;
    if (bid < 256) {
        // projh: (16,1024) = h(16,1024) x W[:, :H]^T + bias
        int b = bid >> 4;
        int oc = bid & 15;
        __shared__ float hrow[HH];
        *(float4*)&hrow[tid * 4] = *(const float4*)(h + (size_t)b * HH + tid * 4);
        __syncthreads();
        int ol = tid >> 2;           // 0..63
        int kq = tid & 3;            // 0..3 (k quarter)
        int o = oc * 64 + ol;
        const float* wr = W + (size_t)o * (2 * HH) + kq * 256;
        const float* hb = hrow + kq * 256;
        float sum = 0.f;
        for (int k = 0; k < 256; k += 4) {
            float4 wv = *(const float4*)(wr + k);
            sum += hb[k] * wv.x + hb[k + 1] * wv.y + hb[k + 2] * wv.z + hb[k + 3] * wv.w;
        }
        sum += __shfl_xor(sum, 1);
        sum += __shfl_xor(sum, 2);
        if (kq == 0) projh[b * HH + o] = sum + bias[o];
    } else if (bid < 320) {
        // convert W[:, H:2H] -> Wb (1024x1024 bf16): 64 blocks x 256 thr x 8 groups x 8 elems
        int cb = bid - 256;
#pragma unroll
        for (int j = 0; j < 8; j++) {
            int g = cb * 2048 + tid + j * 256;
            int o = g >> 7;
            int k = (g & 127) * 8;
            const float* s = W + (size_t)o * (2 * HH) + HH + k;
            float4 a = *(const float4*)(s);
            float4 b2 = *(const float4*)(s + 4);
            union { ushort u[8]; uint4 v; } p;
            p.u[0] = f2bf(a.x); p.u[1] = f2bf(a.y); p.u[2] = f2bf(a.z); p.u[3] = f2bf(a.w);
            p.u[4] = f2bf(b2.x); p.u[5] = f2bf(b2.y); p.u[6] = f2bf(b2.z); p.u[7] = f2bf(b2.w);
            *(uint4*)(Wb + (size_t)o * HH + k) = p.v;
        }
    } else {
        // zero scores (32768 f32) and ctx (16384 f32): 16 blocks
        int zb = bid - 320;
        float4 z = make_float4(0.f, 0.f, 0.f, 0.f);
        float* sp = scores + zb * 2048 + tid * 8;
        *(float4*)(sp) = z;
        *(float4*)(sp + 4) = z;
        *(float4*)(ctx + zb * 1024 + tid * 4) = z;
    }
}

// ---------------- main GEMM: direct global->VGPR fragments, NO LDS, NO barriers ----------------
// 1D grid of 2048 blocks; swizzle keeps the 8 N-siblings of each M-row on the
// same XCD and co-resident (bid%8 round-robin -> XCD), so A fragment re-reads
// are L2-hits. K-loop has zero __syncthreads: register ping-pong prefetch of
// the next K-step's fragments overlaps load latency with MFMA, and the
// compiler is free to use fine-grained vmcnt waits (no barrier drain).
__global__ __launch_bounds__(256, 3) void gemm_scores_kernel(
    const __bf16* __restrict__ Ab,    // (32768,1024) bf16
    const __bf16* __restrict__ Wb,    // (1024,1024) bf16 (cols H..2H of W)
    const float* __restrict__ projh,  // (16,1024) f32
    const float* __restrict__ vW,     // (1024) f32
    float* __restrict__ scores)       // (32768) f32, pre-zeroed
{
    constexpr int BM = 128, BN = 128;

    const int bid = blockIdx.x;
    const int grp = bid >> 6;           // 32 groups of 64 blocks
    const int r   = bid & 63;
    const int n0 = (r >> 3) * BN;       // 8 N-blocks
    const int my = grp * 8 + (r & 7);   // M-row index in [0,256)
    const int m0 = my * BM;
    const int bidx = m0 >> 11;          // batch index (BM=128 divides S=2048)

    const int tid = threadIdx.x;
    const int lane = tid & 63;
    const int wave = tid >> 6;
    const int wm = (wave & 1) * 64;
    const int wn = (wave >> 1) * 64;
    const int quad = lane >> 4;
    const int l16 = lane & 15;

    floatx4 acc[4][4];
    const floatx4 z = {0.f, 0.f, 0.f, 0.f};
#pragma unroll
    for (int i = 0; i < 4; i++)
#pragma unroll
        for (int j = 0; j < 4; j++) acc[i][j] = z;

    // fragment base pointers (k=0); per-k offset is k0 elements
    const __bf16* aptr[4];
    const __bf16* bptr[4];
#pragma unroll
    for (int i = 0; i < 4; i++) {
        aptr[i] = Ab + (size_t)(m0 + wm + i * 16 + l16) * HH + quad * 8;
        bptr[i] = Wb + (size_t)(n0 + wn + i * 16 + l16) * HH + quad * 8;
    }

    bf16x8 af[2][4], bf[2][4];
#pragma unroll
    for (int i = 0; i < 4; i++) {
        af[0][i] = *(const bf16x8*)(aptr[i]);
        bf[0][i] = *(const bf16x8*)(bptr[i]);
    }

    int buf = 0;
    for (int k0 = 0; k0 < HH; k0 += 32, buf ^= 1) {
        int kn = (k0 + 32) & (HH - 1);   // wraps to 0 on last iter (dummy, unused)
#pragma unroll
        for (int i = 0; i < 4; i++) {
            af[buf ^ 1][i] = *(const bf16x8*)(aptr[i] + kn);
            bf[buf ^ 1][i] = *(const bf16x8*)(bptr[i] + kn);
        }
#pragma unroll
        for (int i = 0; i < 4; i++)
#pragma unroll
            for (int j = 0; j < 4; j++)
                acc[i][j] = __builtin_amdgcn_mfma_f32_16x16x32_bf16(af[buf][i], bf[buf][j], acc[i][j], 0, 0, 0);
    }

    // epilogue: scores_partial[m] = sum_n relu(acc + projh[b,n]) * v[n]
    float ph[4], vv[4];
#pragma unroll
    for (int j = 0; j < 4; j++) {
        int ng = n0 + wn + j * 16 + l16;
        ph[j] = projh[bidx * HH + ng];
        vv[j] = vW[ng];
    }
#pragma unroll
    for (int i = 0; i < 4; i++) {
        float s[4] = {0.f, 0.f, 0.f, 0.f};
#pragma unroll
        for (int j = 0; j < 4; j++) {
#pragma unroll
            for (int r2 = 0; r2 < 4; r2++) {
                float e = acc[i][j][r2] + ph[j];
                e = e > 0.f ? e : 0.f;
                s[r2] += e * vv[j];
            }
        }
#pragma unroll
        for (int r2 = 0; r2 < 4; r2++) {
            s[r2] += __shfl_xor(s[r2], 1);
            s[r2] += __shfl_xor(s[r2], 2);
            s[r2] += __shfl_xor(s[r2], 4);
            s[r2] += __shfl_xor(s[r2], 8);
        }
        if (l16 == 0) {
#pragma unroll
            for (int r2 = 0; r2 < 4; r2++) {
                int mg = m0 + wm + i * 16 + quad * 4 + r2;   // D row = quad*4 + reg
                atomicAdd(&scores[mg], s[r2]);
            }
        }
    }
}

// ---------------- fallback GEMM (f32 staging, used if ws too small) ----------------
__global__ __launch_bounds__(256) void gemm_scores_f32_kernel(
    const float* __restrict__ A, const float* __restrict__ W,
    const float* __restrict__ projh, const float* __restrict__ vW,
    float* __restrict__ scores)
{
    constexpr int BM = 128, BN = 128, BK = 32, LDT = BK + 8;
    __shared__ __bf16 As[BM * LDT];
    __shared__ __bf16 Bs[BN * LDT];
    const int n0 = blockIdx.x * BN;
    const int m0 = blockIdx.y * BM;
    const int bidx = m0 >> 11;
    const int tid = threadIdx.x;
    const int lane = tid & 63;
    const int wave = tid >> 6;
    const int wm = (wave & 1) * 64;
    const int wn = (wave >> 1) * 64;
    const int quad = lane >> 4;
    const int l16 = lane & 15;
    floatx4 acc[4][4];
    const floatx4 z = {0.f, 0.f, 0.f, 0.f};
#pragma unroll
    for (int i = 0; i < 4; i++)
#pragma unroll
        for (int j = 0; j < 4; j++) acc[i][j] = z;
    int rowT[4], colT[4];
#pragma unroll
    for (int i = 0; i < 4; i++) {
        int fi = tid + 256 * i;
        rowT[i] = fi >> 3;
        colT[i] = (fi & 7) * 4;
    }
    for (int k0 = 0; k0 < HH; k0 += BK) {
        float4 av[4], bv[4];
#pragma unroll
        for (int i = 0; i < 4; i++) {
            av[i] = *(const float4*)(A + (size_t)(m0 + rowT[i]) * HH + k0 + colT[i]);
            bv[i] = *(const float4*)(W + (size_t)(n0 + rowT[i]) * (2 * HH) + HH + k0 + colT[i]);
        }
        __syncthreads();
#pragma unroll
        for (int i = 0; i < 4; i++) {
            ushort4 ua = make_ushort4(f2bf(av[i].x), f2bf(av[i].y), f2bf(av[i].z), f2bf(av[i].w));
            ushort4 ub = make_ushort4(f2bf(bv[i].x), f2bf(bv[i].y), f2bf(bv[i].z), f2bf(bv[i].w));
            *(ushort4*)&As[rowT[i] * LDT + colT[i]] = ua;
            *(ushort4*)&Bs[rowT[i] * LDT + colT[i]] = ub;
        }
        __syncthreads();
        bf16x8 af[4], bf[4];
#pragma unroll
        for (int i = 0; i < 4; i++)
            af[i] = *(const bf16x8*)&As[(wm + i * 16 + l16) * LDT + quad * 8];
#pragma unroll
        for (int j = 0; j < 4; j++)
            bf[j] = *(const bf16x8*)&Bs[(wn + j * 16 + l16) * LDT + quad * 8];
#pragma unroll
        for (int i = 0; i < 4; i++)
#pragma unroll
            for (int j = 0; j < 4; j++)
                acc[i][j] = __builtin_amdgcn_mfma_f32_16x16x32_bf16(af[i], bf[j], acc[i][j], 0, 0, 0);
    }
    float ph[4], vv[4];
#pragma unroll
    for (int j = 0; j < 4; j++) {
        int ng = n0 + wn + j * 16 + l16;
        ph[j] = projh[bidx * HH + ng];
        vv[j] = vW[ng];
    }
#pragma unroll
    for (int i = 0; i < 4; i++) {
        float s[4] = {0.f, 0.f, 0.f, 0.f};
#pragma unroll
        for (int j = 0; j < 4; j++) {
#pragma unroll
            for (int r = 0; r < 4; r++) {
                float e = acc[i][j][r] + ph[j];
                e = e > 0.f ? e : 0.f;
                s[r] += e * vv[j];
            }
        }
#pragma unroll
        for (int r = 0; r < 4; r++) {
            s[r] += __shfl_xor(s[r], 1);
            s[r] += __shfl_xor(s[r], 2);
            s[r] += __shfl_xor(s[r], 4);
            s[r] += __shfl_xor(s[r], 8);
        }
        if (l16 == 0) {
#pragma unroll
            for (int r = 0; r < 4; r++) {
                int mg = m0 + wm + i * 16 + quad * 4 + r;
                atomicAdd(&scores[mg], s[r]);
            }
        }
    }
}

// ---------------- softmax over S per batch ----------------
__global__ __launch_bounds__(256) void softmax_kernel(
    const float* __restrict__ scores, float* __restrict__ wout)
{
    int b = blockIdx.x;
    int tid = threadIdx.x;
    const float* row = scores + b * SS;
    float x[8];
    float mx = -1e30f;
#pragma unroll
    for (int i = 0; i < 8; i++) { x[i] = row[tid + i * 256]; mx = fmaxf(mx, x[i]); }
#pragma unroll
    for (int off = 32; off; off >>= 1) mx = fmaxf(mx, __shfl_xor(mx, off));
    __shared__ float redm[4], reds[4];
    if ((tid & 63) == 0) redm[tid >> 6] = mx;
    __syncthreads();
    mx = fmaxf(fmaxf(redm[0], redm[1]), fmaxf(redm[2], redm[3]));
    float sum = 0.f;
#pragma unroll
    for (int i = 0; i < 8; i++) { x[i] = __expf(x[i] - mx); sum += x[i]; }
#pragma unroll
    for (int off = 32; off; off >>= 1) sum += __shfl_xor(sum, off);
    if ((tid & 63) == 0) reds[tid >> 6] = sum;
    __syncthreads();
    float inv = 1.0f / (reds[0] + reds[1] + reds[2] + reds[3]);
#pragma unroll
    for (int i = 0; i < 8; i++) wout[b * SS + tid + i * 256] = x[i] * inv;
}

// ---------------- context = weights @ a ----------------
// 512 blocks: 16 b x 32 s-chunks of 64 rows
__global__ __launch_bounds__(256) void context_kernel(
    const float* __restrict__ A, const float* __restrict__ wgt, float* __restrict__ ctx)
{
    int b = blockIdx.x >> 5;
    int sc = blockIdx.x & 31;
    int tid = threadIdx.x;
    const float* arow = A + ((size_t)b * SS + sc * 64) * HH + tid * 4;
    const float* wrow = wgt + b * SS + sc * 64;
    float4 acc = make_float4(0.f, 0.f, 0.f, 0.f);
#pragma unroll 4
    for (int s = 0; s < 64; s++) {
        float w = wrow[s];
        float4 v = *(const float4*)(arow + (size_t)s * HH);
        acc.x += w * v.x; acc.y += w * v.y; acc.z += w * v.z; acc.w += w * v.w;
    }
    float* o = ctx + b * HH + tid * 4;
    atomicAdd(o + 0, acc.x);
    atomicAdd(o + 1, acc.y);
    atomicAdd(o + 2, acc.z);
    atomicAdd(o + 3, acc.w);
}

extern "C" void kernel_launch(void* const* d_in, const int* in_sizes, int n_in,
                              void* d_out, int out_size, void* d_ws, size_t ws_size,
                              hipStream_t stream) {
    const float* h    = (const float*)d_in[0];
    // d_in[1] = c (unused by reference)
    const float* a    = (const float*)d_in[2];
    const float* W    = (const float*)d_in[3];
    const float* bias = (const float*)d_in[4];
    const float* vW   = (const float*)d_in[5];
    float* out = (float*)d_out;

    float* projh  = (float*)d_ws;              // 16384 f32  (64 KB)
    float* scores = projh + BB * HH;           // 32768 f32  (128 KB)
    __bf16* Wb = (__bf16*)(scores + MM);       // 1M bf16    (2 MB)
    __bf16* Ab = Wb + (size_t)HH * HH;         // 33.5M bf16 (67.1 MB)
    const size_t need = (size_t)(BB * HH + MM) * 4 + (size_t)HH * HH * 2
                      + (size_t)MM * HH * 2;

    if (ws_size >= need) {
        prep_kernel<<<336, 256, 0, stream>>>(h, W, bias, projh, Wb, scores, out);
        convert_A_kernel<<<(MM * HH / 8) / 256, 256, 0, stream>>>(a, Ab);
        gemm_scores_kernel<<<2048, 256, 0, stream>>>(Ab, Wb, projh, vW, scores);
    } else {
        prep_kernel<<<336, 256, 0, stream>>>(h, W, bias, projh, Wb, scores, out);
        gemm_scores_f32_kernel<<<dim3(HH / 128, MM / 128), 256, 0, stream>>>(a, W, projh, vW, scores);
    }

    softmax_kernel<<<BB, 256, 0, stream>>>(scores, out + BB * HH);
    context_kernel<<<BB * 32, 256, 0, stream>>>(a, out + BB * HH, out);
}

// Round 5
// 309.139 us; speedup vs baseline: 1.6376x; 1.6376x over previous
//
#include <hip/hip_runtime.h>
#include <hip/hip_bf16.h>

// Problem: B=16, S=2048, H=1024
//   a = encoder_outputs (B,S,H) f32
//   projh[b,o] = sum_h h[b,h]*W[o,h] + bias[o]
//   scores[b,s] = sum_o relu( sum_h a[b,s,h]*W[o,H+h] + projh[b,o] ) * v[o]
//   weights = softmax_s(scores); context[b,h] = sum_s weights[b,s]*a[b,s,h]
// Outputs concat: context (16*1024 f32) then weights (16*2048 f32)

typedef __bf16 bf16x8 __attribute__((ext_vector_type(8)));
typedef float floatx4 __attribute__((ext_vector_type(4)));

#define BB 16
#define SS 2048
#define HH 1024
#define MM (BB * SS)

#define GLB(p) ((const __attribute__((address_space(1))) void*)(p))
#define LDSP(p) ((__attribute__((address_space(3))) void*)(p))

__device__ inline ushort f2bf(float x) {
    uint32_t u = __builtin_bit_cast(uint32_t, x);
    u += 0x7FFFu + ((u >> 16) & 1u);   // round-to-nearest-even
    return (ushort)(u >> 16);
}

// ---------------- f32 -> bf16 bulk convert (A: 33.5M elems) ----------------
__global__ __launch_bounds__(256) void convert_A_kernel(
    const float* __restrict__ src, __bf16* __restrict__ dst)
{
    size_t i = (size_t)blockIdx.x * 256 + threadIdx.x;   // 8-elem group
    const float* s = src + i * 8;
    float4 a = *(const float4*)(s);
    float4 b = *(const float4*)(s + 4);
    union { ushort u[8]; uint4 v; } p;
    p.u[0] = f2bf(a.x); p.u[1] = f2bf(a.y); p.u[2] = f2bf(a.z); p.u[3] = f2bf(a.w);
    p.u[4] = f2bf(b.x); p.u[5] = f2bf(b.y); p.u[6] = f2bf(b.z); p.u[7] = f2bf(b.w);
    *(uint4*)(dst + i * 8) = p.v;
}

// ---------------- prep: projh (blocks 0..255) + convert_W (256..319) + zero (320..335) ----
__global__ __launch_bounds__(256) void prep_kernel(
    const float* __restrict__ h, const float* __restrict__ W,
    const float* __restrict__ bias, float* __restrict__ projh,
    __bf16* __restrict__ Wb, float* __restrict__ scores, float* __restrict__ ctx)
{
    int bid = blockIdx.x;
    int tid = threadIdx.x;
    if (bid < 256) {
        // projh: (16,1024) = h(16,1024) x W[:, :H]^T + bias
        int b = bid >> 4;
        int oc = bid & 15;
        __shared__ float hrow[HH];
        *(float4*)&hrow[tid * 4] = *(const float4*)(h + (size_t)b * HH + tid * 4);
        __syncthreads();
        int ol = tid >> 2;           // 0..63
        int kq = tid & 3;            // 0..3 (k quarter)
        int o = oc * 64 + ol;
        const float* wr = W + (size_t)o * (2 * HH) + kq * 256;
        const float* hb = hrow + kq * 256;
        float sum = 0.f;
        for (int k = 0; k < 256; k += 4) {
            float4 wv = *(const float4*)(wr + k);
            sum += hb[k] * wv.x + hb[k + 1] * wv.y + hb[k + 2] * wv.z + hb[k + 3] * wv.w;
        }
        sum += __shfl_xor(sum, 1);
        sum += __shfl_xor(sum, 2);
        if (kq == 0) projh[b * HH + o] = sum + bias[o];
    } else if (bid < 320) {
        // convert W[:, H:2H] -> Wb (1024x1024 bf16): 64 blocks x 256 thr x 8 groups x 8 elems
        int cb = bid - 256;
#pragma unroll
        for (int j = 0; j < 8; j++) {
            int g = cb * 2048 + tid + j * 256;
            int o = g >> 7;
            int k = (g & 127) * 8;
            const float* s = W + (size_t)o * (2 * HH) + HH + k;
            float4 a = *(const float4*)(s);
            float4 b2 = *(const float4*)(s + 4);
            union { ushort u[8]; uint4 v; } p;
            p.u[0] = f2bf(a.x); p.u[1] = f2bf(a.y); p.u[2] = f2bf(a.z); p.u[3] = f2bf(a.w);
            p.u[4] = f2bf(b2.x); p.u[5] = f2bf(b2.y); p.u[6] = f2bf(b2.z); p.u[7] = f2bf(b2.w);
            *(uint4*)(Wb + (size_t)o * HH + k) = p.v;
        }
    } else {
        // zero scores (32768 f32) and ctx (16384 f32): 16 blocks
        int zb = bid - 320;
        float4 z = make_float4(0.f, 0.f, 0.f, 0.f);
        float* sp = scores + zb * 2048 + tid * 8;
        *(float4*)(sp) = z;
        *(float4*)(sp + 4) = z;
        *(float4*)(ctx + zb * 1024 + tid * 4) = z;
    }
}

// ---------------- main GEMM: 256x256 tile, 8 waves, BK=32, LDS double-buffer ----------------
// One barrier per K-stage; stage s+1's global_load_lds are issued BEFORE stage s's
// compute, so the barrier's implicit vmcnt(0) drain hits loads that already had a
// full compute phase (~1500 cyc) to land. 512 blocks; swizzle keeps the 4
// N-siblings of each M-row on one XCD (bid%8 round-robin) for A-tile L2 reuse.
// LDS chunk layout XOR-swizzled (verified 0 bank conflicts in rounds 2-3).
__global__ __launch_bounds__(512, 2) void gemm_scores_kernel(
    const __bf16* __restrict__ Ab,    // (32768,1024) bf16
    const __bf16* __restrict__ Wb,    // (1024,1024) bf16 (cols H..2H of W)
    const float* __restrict__ projh,  // (16,1024) f32
    const float* __restrict__ vW,     // (1024) f32
    float* __restrict__ scores)       // (32768) f32, pre-zeroed
{
    __shared__ __bf16 smem[32768];    // 64 KB: 2 bufs x (As 8192 | Bs 8192 elems)

    const int bid = blockIdx.x;
    const int m0 = (((bid >> 5) << 3) + (bid & 7)) * 256;  // 128 M-tiles
    const int n0 = ((bid >> 3) & 3) * 256;                 // 4 N-tiles
    const int bidx = m0 >> 11;        // batch index (256 divides 2048)

    const int tid = threadIdx.x;
    const int lane = tid & 63;
    const int wave = tid >> 6;        // 0..7
    const int wm = (wave & 1) * 128;  // wave tile: 128 (M) x 64 (N)
    const int wn = (wave >> 1) * 64;
    const int quad = lane >> 4;
    const int l16 = lane & 15;

    floatx4 acc[8][4];
    const floatx4 z = {0.f, 0.f, 0.f, 0.f};
#pragma unroll
    for (int i = 0; i < 8; i++)
#pragma unroll
        for (int j = 0; j < 4; j++) acc[i][j] = z;

    // ---- staging gather addresses (chunk c = tid and tid+512; +512 => row+128) ----
    {
    }
    const int su = tid >> 3;
    const int sj = (tid & 7) ^ (su & 7);
    const int g_row = su * 2 + (sj >> 2);
    const int g_col = (sj & 3) * 8;
    const __bf16* gA  = Ab + (size_t)(m0 + g_row) * HH + g_col;
    const __bf16* gA2 = gA + (size_t)128 * HH;
    const __bf16* gB  = Wb + (size_t)(n0 + g_row) * HH + g_col;
    const __bf16* gB2 = gB + (size_t)128 * HH;
    const int ldsb = wave * 512;      // wave-uniform chunk base (elems)

    // ---- fragment LDS element offsets (k-invariant, XOR-swizzled) ----
    int aoff[8], boff[4];
#pragma unroll
    for (int i = 0; i < 8; i++) {
        int frow = wm + i * 16 + l16;
        int u2 = frow >> 1;
        int cc = u2 * 8 + (((((frow & 1) << 2) | quad)) ^ (u2 & 7));
        aoff[i] = cc * 8;
    }
#pragma unroll
    for (int j = 0; j < 4; j++) {
        int frow = wn + j * 16 + l16;
        int u2 = frow >> 1;
        int cc = u2 * 8 + (((((frow & 1) << 2) | quad)) ^ (u2 & 7));
        boff[j] = 8192 + cc * 8;
    }

#define ISSUE_STAGE(buf, k0)                                                          \
    {                                                                                 \
        __bf16* dst = smem + (buf) * 16384 + ldsb;                                    \
        __builtin_amdgcn_global_load_lds(GLB(gA  + (k0)), LDSP(dst),         16, 0, 0); \
        __builtin_amdgcn_global_load_lds(GLB(gA2 + (k0)), LDSP(dst + 4096),  16, 0, 0); \
        __builtin_amdgcn_global_load_lds(GLB(gB  + (k0)), LDSP(dst + 8192),  16, 0, 0); \
        __builtin_amdgcn_global_load_lds(GLB(gB2 + (k0)), LDSP(dst + 12288), 16, 0, 0); \
    }

    ISSUE_STAGE(0, 0)
    for (int s = 0; s < 32; s++) {
        __syncthreads();   // drains buf[s&1] loads (issued a full stage ago)
        if (s < 31) ISSUE_STAGE((s + 1) & 1, (s + 1) * 32)
        const __bf16* sb = smem + (s & 1) * 16384;
        bf16x8 af[8], bfr[4];
#pragma unroll
        for (int j = 0; j < 4; j++) bfr[j] = *(const bf16x8*)(sb + boff[j]);
#pragma unroll
        for (int i = 0; i < 8; i++) af[i] = *(const bf16x8*)(sb + aoff[i]);
#pragma unroll
        for (int i = 0; i < 8; i++)
#pragma unroll
            for (int j = 0; j < 4; j++)
                acc[i][j] = __builtin_amdgcn_mfma_f32_16x16x32_bf16(af[i], bfr[j], acc[i][j], 0, 0, 0);
    }
#undef ISSUE_STAGE

    // epilogue: scores_partial[m] = sum_n relu(acc + projh[b,n]) * v[n]
    float ph[4], vv[4];
#pragma unroll
    for (int j = 0; j < 4; j++) {
        int ng = n0 + wn + j * 16 + l16;
        ph[j] = projh[bidx * HH + ng];
        vv[j] = vW[ng];
    }
#pragma unroll
    for (int i = 0; i < 8; i++) {
        float s[4] = {0.f, 0.f, 0.f, 0.f};
#pragma unroll
        for (int j = 0; j < 4; j++) {
#pragma unroll
            for (int r2 = 0; r2 < 4; r2++) {
                float e = acc[i][j][r2] + ph[j];
                e = e > 0.f ? e : 0.f;
                s[r2] += e * vv[j];
            }
        }
#pragma unroll
        for (int r2 = 0; r2 < 4; r2++) {
            s[r2] += __shfl_xor(s[r2], 1);
            s[r2] += __shfl_xor(s[r2], 2);
            s[r2] += __shfl_xor(s[r2], 4);
            s[r2] += __shfl_xor(s[r2], 8);
        }
        if (l16 == 0) {
#pragma unroll
            for (int r2 = 0; r2 < 4; r2++) {
                int mg = m0 + wm + i * 16 + quad * 4 + r2;   // D row = quad*4 + reg
                atomicAdd(&scores[mg], s[r2]);
            }
        }
    }
}

// ---------------- fallback GEMM (f32 staging, used if ws too small) ----------------
__global__ __launch_bounds__(256) void gemm_scores_f32_kernel(
    const float* __restrict__ A, const float* __restrict__ W,
    const float* __restrict__ projh, const float* __restrict__ vW,
    float* __restrict__ scores)
{
    constexpr int BM = 128, BN = 128, BK = 32, LDT = BK + 8;
    __shared__ __bf16 As[BM * LDT];
    __shared__ __bf16 Bs[BN * LDT];
    const int n0 = blockIdx.x * BN;
    const int m0 = blockIdx.y * BM;
    const int bidx = m0 >> 11;
    const int tid = threadIdx.x;
    const int lane = tid & 63;
    const int wave = tid >> 6;
    const int wm = (wave & 1) * 64;
    const int wn = (wave >> 1) * 64;
    const int quad = lane >> 4;
    const int l16 = lane & 15;
    floatx4 acc[4][4];
    const floatx4 z = {0.f, 0.f, 0.f, 0.f};
#pragma unroll
    for (int i = 0; i < 4; i++)
#pragma unroll
        for (int j = 0; j < 4; j++) acc[i][j] = z;
    int rowT[4], colT[4];
#pragma unroll
    for (int i = 0; i < 4; i++) {
        int fi = tid + 256 * i;
        rowT[i] = fi >> 3;
        colT[i] = (fi & 7) * 4;
    }
    for (int k0 = 0; k0 < HH; k0 += BK) {
        float4 av[4], bv[4];
#pragma unroll
        for (int i = 0; i < 4; i++) {
            av[i] = *(const float4*)(A + (size_t)(m0 + rowT[i]) * HH + k0 + colT[i]);
            bv[i] = *(const float4*)(W + (size_t)(n0 + rowT[i]) * (2 * HH) + HH + k0 + colT[i]);
        }
        __syncthreads();
#pragma unroll
        for (int i = 0; i < 4; i++) {
            ushort4 ua = make_ushort4(f2bf(av[i].x), f2bf(av[i].y), f2bf(av[i].z), f2bf(av[i].w));
            ushort4 ub = make_ushort4(f2bf(bv[i].x), f2bf(bv[i].y), f2bf(bv[i].z), f2bf(bv[i].w));
            *(ushort4*)&As[rowT[i] * LDT + colT[i]] = ua;
            *(ushort4*)&Bs[rowT[i] * LDT + colT[i]] = ub;
        }
        __syncthreads();
        bf16x8 af[4], bf[4];
#pragma unroll
        for (int i = 0; i < 4; i++)
            af[i] = *(const bf16x8*)&As[(wm + i * 16 + l16) * LDT + quad * 8];
#pragma unroll
        for (int j = 0; j < 4; j++)
            bf[j] = *(const bf16x8*)&Bs[(wn + j * 16 + l16) * LDT + quad * 8];
#pragma unroll
        for (int i = 0; i < 4; i++)
#pragma unroll
            for (int j = 0; j < 4; j++)
                acc[i][j] = __builtin_amdgcn_mfma_f32_16x16x32_bf16(af[i], bf[j], acc[i][j], 0, 0, 0);
    }
    float ph[4], vv[4];
#pragma unroll
    for (int j = 0; j < 4; j++) {
        int ng = n0 + wn + j * 16 + l16;
        ph[j] = projh[bidx * HH + ng];
        vv[j] = vW[ng];
    }
#pragma unroll
    for (int i = 0; i < 4; i++) {
        float s[4] = {0.f, 0.f, 0.f, 0.f};
#pragma unroll
        for (int j = 0; j < 4; j++) {
#pragma unroll
            for (int r = 0; r < 4; r++) {
                float e = acc[i][j][r] + ph[j];
                e = e > 0.f ? e : 0.f;
                s[r] += e * vv[j];
            }
        }
#pragma unroll
        for (int r = 0; r < 4; r++) {
            s[r] += __shfl_xor(s[r], 1);
            s[r] += __shfl_xor(s[r], 2);
            s[r] += __shfl_xor(s[r], 4);
            s[r] += __shfl_xor(s[r], 8);
        }
        if (l16 == 0) {
#pragma unroll
            for (int r = 0; r < 4; r++) {
                int mg = m0 + wm + i * 16 + quad * 4 + r;
                atomicAdd(&scores[mg], s[r]);
            }
        }
    }
}

// ---------------- softmax over S per batch ----------------
__global__ __launch_bounds__(256) void softmax_kernel(
    const float* __restrict__ scores, float* __restrict__ wout)
{
    int b = blockIdx.x;
    int tid = threadIdx.x;
    const float* row = scores + b * SS;
    float x[8];
    float mx = -1e30f;
#pragma unroll
    for (int i = 0; i < 8; i++) { x[i] = row[tid + i * 256]; mx = fmaxf(mx, x[i]); }
#pragma unroll
    for (int off = 32; off; off >>= 1) mx = fmaxf(mx, __shfl_xor(mx, off));
    __shared__ float redm[4], reds[4];
    if ((tid & 63) == 0) redm[tid >> 6] = mx;
    __syncthreads();
    mx = fmaxf(fmaxf(redm[0], redm[1]), fmaxf(redm[2], redm[3]));
    float sum = 0.f;
#pragma unroll
    for (int i = 0; i < 8; i++) { x[i] = __expf(x[i] - mx); sum += x[i]; }
#pragma unroll
    for (int off = 32; off; off >>= 1) sum += __shfl_xor(sum, off);
    if ((tid & 63) == 0) reds[tid >> 6] = sum;
    __syncthreads();
    float inv = 1.0f / (reds[0] + reds[1] + reds[2] + reds[3]);
#pragma unroll
    for (int i = 0; i < 8; i++) wout[b * SS + tid + i * 256] = x[i] * inv;
}

// ---------------- context = weights @ a ----------------
// 512 blocks: 16 b x 32 s-chunks of 64 rows
__global__ __launch_bounds__(256) void context_kernel(
    const float* __restrict__ A, const float* __restrict__ wgt, float* __restrict__ ctx)
{
    int b = blockIdx.x >> 5;
    int sc = blockIdx.x & 31;
    int tid = threadIdx.x;
    const float* arow = A + ((size_t)b * SS + sc * 64) * HH + tid * 4;
    const float* wrow = wgt + b * SS + sc * 64;
    float4 acc = make_float4(0.f, 0.f, 0.f, 0.f);
#pragma unroll 4
    for (int s = 0; s < 64; s++) {
        float w = wrow[s];
        float4 v = *(const float4*)(arow + (size_t)s * HH);
        acc.x += w * v.x; acc.y += w * v.y; acc.z += w * v.z; acc.w += w * v.w;
    }
    float* o = ctx + b * HH + tid * 4;
    atomicAdd(o + 0, acc.x);
    atomicAdd(o + 1, acc.y);
    atomicAdd(o + 2, acc.z);
    atomicAdd(o + 3, acc.w);
}

extern "C" void kernel_launch(void* const* d_in, const int* in_sizes, int n_in,
                              void* d_out, int out_size, void* d_ws, size_t ws_size,
                              hipStream_t stream) {
    const float* h    = (const float*)d_in[0];
    // d_in[1] = c (unused by reference)
    const float* a    = (const float*)d_in[2];
    const float* W    = (const float*)d_in[3];
    const float* bias = (const float*)d_in[4];
    const float* vW   = (const float*)d_in[5];
    float* out = (float*)d_out;

    float* projh  = (float*)d_ws;              // 16384 f32  (64 KB)
    float* scores = projh + BB * HH;           // 32768 f32  (128 KB)
    __bf16* Wb = (__bf16*)(scores + MM);       // 1M bf16    (2 MB)
    __bf16* Ab = Wb + (size_t)HH * HH;         // 33.5M bf16 (67.1 MB)
    const size_t need = (size_t)(BB * HH + MM) * 4 + (size_t)HH * HH * 2
                      + (size_t)MM * HH * 2;

    if (ws_size >= need) {
        prep_kernel<<<336, 256, 0, stream>>>(h, W, bias, projh, Wb, scores, out);
        convert_A_kernel<<<(MM * HH / 8) / 256, 256, 0, stream>>>(a, Ab);
        gemm_scores_kernel<<<512, 512, 0, stream>>>(Ab, Wb, projh, vW, scores);
    } else {
        prep_kernel<<<336, 256, 0, stream>>>(h, W, bias, projh, Wb, scores, out);
        gemm_scores_f32_kernel<<<dim3(HH / 128, MM / 128), 256, 0, stream>>>(a, W, projh, vW, scores);
    }

    softmax_kernel<<<BB, 256, 0, stream>>>(scores, out + BB * HH);
    context_kernel<<<BB * 32, 256, 0, stream>>>(a, out + BB * HH, out);
}

// Round 6
// 295.033 us; speedup vs baseline: 1.7159x; 1.0478x over previous
//
#include <hip/hip_runtime.h>
#include <hip/hip_bf16.h>

// Problem: B=16, S=2048, H=1024
//   a = encoder_outputs (B,S,H) f32
//   projh[b,o] = sum_h h[b,h]*W[o,h] + bias[o]
//   scores[b,s] = sum_o relu( sum_h a[b,s,h]*W[o,H+h] + projh[b,o] ) * v[o]
//   weights = softmax_s(scores); context[b,h] = sum_s weights[b,s]*a[b,s,h]
// Outputs concat: context (16*1024 f32) then weights (16*2048 f32)
//
// 3 dispatches: prep_all (projh+convert_W+zero+convert_A) -> gemm -> softmax_context.

typedef __bf16 bf16x8 __attribute__((ext_vector_type(8)));
typedef float floatx4 __attribute__((ext_vector_type(4)));

#define BB 16
#define SS 2048
#define HH 1024
#define MM (BB * SS)

#define GLB(p) ((const __attribute__((address_space(1))) void*)(p))
#define LDSP(p) ((__attribute__((address_space(3))) void*)(p))

__device__ inline ushort f2bf(float x) {
    uint32_t u = __builtin_bit_cast(uint32_t, x);
    u += 0x7FFFu + ((u >> 16) & 1u);   // round-to-nearest-even
    return (ushort)(u >> 16);
}

// ---------------- prep_all ----------------
// bids [0,256): projh; [256,320): convert_W; [320,336): zero scores+ctx;
// [336,16720): convert_A (f32 -> bf16, 33.5M elems).
__global__ __launch_bounds__(256) void prep_all_kernel(
    const float* __restrict__ h, const float* __restrict__ W,
    const float* __restrict__ bias, const float* __restrict__ a,
    float* __restrict__ projh, __bf16* __restrict__ Wb, __bf16* __restrict__ Ab,
    float* __restrict__ scores, float* __restrict__ ctx)
{
    int bid = blockIdx.x;
    int tid = threadIdx.x;
    if (bid >= 336) {
        size_t i = (size_t)(bid - 336) * 256 + tid;   // 8-elem group
        const float* s = a + i * 8;
        float4 x = *(const float4*)(s);
        float4 y = *(const float4*)(s + 4);
        union { ushort u[8]; uint4 v; } p;
        p.u[0] = f2bf(x.x); p.u[1] = f2bf(x.y); p.u[2] = f2bf(x.z); p.u[3] = f2bf(x.w);
        p.u[4] = f2bf(y.x); p.u[5] = f2bf(y.y); p.u[6] = f2bf(y.z); p.u[7] = f2bf(y.w);
        *(uint4*)(Ab + i * 8) = p.v;
    } else if (bid < 256) {
        // projh: (16,1024) = h(16,1024) x W[:, :H]^T + bias
        int b = bid >> 4;
        int oc = bid & 15;
        __shared__ float hrow[HH];
        *(float4*)&hrow[tid * 4] = *(const float4*)(h + (size_t)b * HH + tid * 4);
        __syncthreads();
        int ol = tid >> 2;           // 0..63
        int kq = tid & 3;            // 0..3 (k quarter)
        int o = oc * 64 + ol;
        const float* wr = W + (size_t)o * (2 * HH) + kq * 256;
        const float* hb = hrow + kq * 256;
        float sum = 0.f;
        for (int k = 0; k < 256; k += 4) {
            float4 wv = *(const float4*)(wr + k);
            sum += hb[k] * wv.x + hb[k + 1] * wv.y + hb[k + 2] * wv.z + hb[k + 3] * wv.w;
        }
        sum += __shfl_xor(sum, 1);
        sum += __shfl_xor(sum, 2);
        if (kq == 0) projh[b * HH + o] = sum + bias[o];
    } else if (bid < 320) {
        // convert W[:, H:2H] -> Wb (1024x1024 bf16)
        int cb = bid - 256;
#pragma unroll
        for (int j = 0; j < 8; j++) {
            int g = cb * 2048 + tid + j * 256;
            int o = g >> 7;
            int k = (g & 127) * 8;
            const float* s = W + (size_t)o * (2 * HH) + HH + k;
            float4 x = *(const float4*)(s);
            float4 y = *(const float4*)(s + 4);
            union { ushort u[8]; uint4 v; } p;
            p.u[0] = f2bf(x.x); p.u[1] = f2bf(x.y); p.u[2] = f2bf(x.z); p.u[3] = f2bf(x.w);
            p.u[4] = f2bf(y.x); p.u[5] = f2bf(y.y); p.u[6] = f2bf(y.z); p.u[7] = f2bf(y.w);
            *(uint4*)(Wb + (size_t)o * HH + k) = p.v;
        }
    } else {
        // zero scores (32768 f32) and ctx (16384 f32): 16 blocks
        int zb = bid - 320;
        float4 z = make_float4(0.f, 0.f, 0.f, 0.f);
        float* sp = scores + zb * 2048 + tid * 8;
        *(float4*)(sp) = z;
        *(float4*)(sp + 4) = z;
        *(float4*)(ctx + zb * 1024 + tid * 4) = z;
    }
}

// ---------------- main GEMM: 256x256 tile, 8 waves, BK=32, LDS double-buffer ----------------
// (unchanged from round 5 — at the documented m97-structure plateau, 78 us)
// One barrier per K-stage; stage s+1's global_load_lds are issued BEFORE stage s's
// compute. 512 blocks; swizzle keeps the 4 N-siblings of each M-row on one XCD.
// LDS chunk layout XOR-swizzled (verified 0 bank conflicts).
__global__ __launch_bounds__(512, 2) void gemm_scores_kernel(
    const __bf16* __restrict__ Ab,    // (32768,1024) bf16
    const __bf16* __restrict__ Wb,    // (1024,1024) bf16 (cols H..2H of W)
    const float* __restrict__ projh,  // (16,1024) f32
    const float* __restrict__ vW,     // (1024) f32
    float* __restrict__ scores)       // (32768) f32, pre-zeroed
{
    __shared__ __bf16 smem[32768];    // 64 KB: 2 bufs x (As 8192 | Bs 8192 elems)

    const int bid = blockIdx.x;
    const int m0 = (((bid >> 5) << 3) + (bid & 7)) * 256;  // 128 M-tiles
    const int n0 = ((bid >> 3) & 3) * 256;                 // 4 N-tiles
    const int bidx = m0 >> 11;        // batch index (256 divides 2048)

    const int tid = threadIdx.x;
    const int lane = tid & 63;
    const int wave = tid >> 6;        // 0..7
    const int wm = (wave & 1) * 128;  // wave tile: 128 (M) x 64 (N)
    const int wn = (wave >> 1) * 64;
    const int quad = lane >> 4;
    const int l16 = lane & 15;

    floatx4 acc[8][4];
    const floatx4 z = {0.f, 0.f, 0.f, 0.f};
#pragma unroll
    for (int i = 0; i < 8; i++)
#pragma unroll
        for (int j = 0; j < 4; j++) acc[i][j] = z;

    const int su = tid >> 3;
    const int sj = (tid & 7) ^ (su & 7);
    const int g_row = su * 2 + (sj >> 2);
    const int g_col = (sj & 3) * 8;
    const __bf16* gA  = Ab + (size_t)(m0 + g_row) * HH + g_col;
    const __bf16* gA2 = gA + (size_t)128 * HH;
    const __bf16* gB  = Wb + (size_t)(n0 + g_row) * HH + g_col;
    const __bf16* gB2 = gB + (size_t)128 * HH;
    const int ldsb = wave * 512;      // wave-uniform chunk base (elems)

    int aoff[8], boff[4];
#pragma unroll
    for (int i = 0; i < 8; i++) {
        int frow = wm + i * 16 + l16;
        int u2 = frow >> 1;
        int cc = u2 * 8 + (((((frow & 1) << 2) | quad)) ^ (u2 & 7));
        aoff[i] = cc * 8;
    }
#pragma unroll
    for (int j = 0; j < 4; j++) {
        int frow = wn + j * 16 + l16;
        int u2 = frow >> 1;
        int cc = u2 * 8 + (((((frow & 1) << 2) | quad)) ^ (u2 & 7));
        boff[j] = 8192 + cc * 8;
    }

#define ISSUE_STAGE(buf, k0)                                                          \
    {                                                                                 \
        __bf16* dst = smem + (buf) * 16384 + ldsb;                                    \
        __builtin_amdgcn_global_load_lds(GLB(gA  + (k0)), LDSP(dst),         16, 0, 0); \
        __builtin_amdgcn_global_load_lds(GLB(gA2 + (k0)), LDSP(dst + 4096),  16, 0, 0); \
        __builtin_amdgcn_global_load_lds(GLB(gB  + (k0)), LDSP(dst + 8192),  16, 0, 0); \
        __builtin_amdgcn_global_load_lds(GLB(gB2 + (k0)), LDSP(dst + 12288), 16, 0, 0); \
    }

    ISSUE_STAGE(0, 0)
    for (int s = 0; s < 32; s++) {
        __syncthreads();   // drains buf[s&1] loads (issued a full stage ago)
        if (s < 31) ISSUE_STAGE((s + 1) & 1, (s + 1) * 32)
        const __bf16* sb = smem + (s & 1) * 16384;
        bf16x8 af[8], bfr[4];
#pragma unroll
        for (int j = 0; j < 4; j++) bfr[j] = *(const bf16x8*)(sb + boff[j]);
#pragma unroll
        for (int i = 0; i < 8; i++) af[i] = *(const bf16x8*)(sb + aoff[i]);
#pragma unroll
        for (int i = 0; i < 8; i++)
#pragma unroll
            for (int j = 0; j < 4; j++)
                acc[i][j] = __builtin_amdgcn_mfma_f32_16x16x32_bf16(af[i], bfr[j], acc[i][j], 0, 0, 0);
    }
#undef ISSUE_STAGE

    // epilogue: scores_partial[m] = sum_n relu(acc + projh[b,n]) * v[n]
    float ph[4], vv[4];
#pragma unroll
    for (int j = 0; j < 4; j++) {
        int ng = n0 + wn + j * 16 + l16;
        ph[j] = projh[bidx * HH + ng];
        vv[j] = vW[ng];
    }
#pragma unroll
    for (int i = 0; i < 8; i++) {
        float s[4] = {0.f, 0.f, 0.f, 0.f};
#pragma unroll
        for (int j = 0; j < 4; j++) {
#pragma unroll
            for (int r2 = 0; r2 < 4; r2++) {
                float e = acc[i][j][r2] + ph[j];
                e = e > 0.f ? e : 0.f;
                s[r2] += e * vv[j];
            }
        }
#pragma unroll
        for (int r2 = 0; r2 < 4; r2++) {
            s[r2] += __shfl_xor(s[r2], 1);
            s[r2] += __shfl_xor(s[r2], 2);
            s[r2] += __shfl_xor(s[r2], 4);
            s[r2] += __shfl_xor(s[r2], 8);
        }
        if (l16 == 0) {
#pragma unroll
            for (int r2 = 0; r2 < 4; r2++) {
                int mg = m0 + wm + i * 16 + quad * 4 + r2;   // D row = quad*4 + reg
                atomicAdd(&scores[mg], s[r2]);
            }
        }
    }
}

// ---------------- fallback GEMM (f32 staging, used if ws too small) ----------------
__global__ __launch_bounds__(256) void gemm_scores_f32_kernel(
    const float* __restrict__ A, const float* __restrict__ W,
    const float* __restrict__ projh, const float* __restrict__ vW,
    float* __restrict__ scores)
{
    constexpr int BM = 128, BN = 128, BK = 32, LDT = BK + 8;
    __shared__ __bf16 As[BM * LDT];
    __shared__ __bf16 Bs[BN * LDT];
    const int n0 = blockIdx.x * BN;
    const int m0 = blockIdx.y * BM;
    const int bidx = m0 >> 11;
    const int tid = threadIdx.x;
    const int lane = tid & 63;
    const int wave = tid >> 6;
    const int wm = (wave & 1) * 64;
    const int wn = (wave >> 1) * 64;
    const int quad = lane >> 4;
    const int l16 = lane & 15;
    floatx4 acc[4][4];
    const floatx4 z = {0.f, 0.f, 0.f, 0.f};
#pragma unroll
    for (int i = 0; i < 4; i++)
#pragma unroll
        for (int j = 0; j < 4; j++) acc[i][j] = z;
    int rowT[4], colT[4];
#pragma unroll
    for (int i = 0; i < 4; i++) {
        int fi = tid + 256 * i;
        rowT[i] = fi >> 3;
        colT[i] = (fi & 7) * 4;
    }
    for (int k0 = 0; k0 < HH; k0 += BK) {
        float4 av[4], bv[4];
#pragma unroll
        for (int i = 0; i < 4; i++) {
            av[i] = *(const float4*)(A + (size_t)(m0 + rowT[i]) * HH + k0 + colT[i]);
            bv[i] = *(const float4*)(W + (size_t)(n0 + rowT[i]) * (2 * HH) + HH + k0 + colT[i]);
        }
        __syncthreads();
#pragma unroll
        for (int i = 0; i < 4; i++) {
            ushort4 ua = make_ushort4(f2bf(av[i].x), f2bf(av[i].y), f2bf(av[i].z), f2bf(av[i].w));
            ushort4 ub = make_ushort4(f2bf(bv[i].x), f2bf(bv[i].y), f2bf(bv[i].z), f2bf(bv[i].w));
            *(ushort4*)&As[rowT[i] * LDT + colT[i]] = ua;
            *(ushort4*)&Bs[rowT[i] * LDT + colT[i]] = ub;
        }
        __syncthreads();
        bf16x8 af[4], bf[4];
#pragma unroll
        for (int i = 0; i < 4; i++)
            af[i] = *(const bf16x8*)&As[(wm + i * 16 + l16) * LDT + quad * 8];
#pragma unroll
        for (int j = 0; j < 4; j++)
            bf[j] = *(const bf16x8*)&Bs[(wn + j * 16 + l16) * LDT + quad * 8];
#pragma unroll
        for (int i = 0; i < 4; i++)
#pragma unroll
            for (int j = 0; j < 4; j++)
                acc[i][j] = __builtin_amdgcn_mfma_f32_16x16x32_bf16(af[i], bf[j], acc[i][j], 0, 0, 0);
    }
    float ph[4], vv[4];
#pragma unroll
    for (int j = 0; j < 4; j++) {
        int ng = n0 + wn + j * 16 + l16;
        ph[j] = projh[bidx * HH + ng];
        vv[j] = vW[ng];
    }
#pragma unroll
    for (int i = 0; i < 4; i++) {
        float s[4] = {0.f, 0.f, 0.f, 0.f};
#pragma unroll
        for (int j = 0; j < 4; j++) {
#pragma unroll
            for (int r = 0; r < 4; r++) {
                float e = acc[i][j][r] + ph[j];
                e = e > 0.f ? e : 0.f;
                s[r] += e * vv[j];
            }
        }
#pragma unroll
        for (int r = 0; r < 4; r++) {
            s[r] += __shfl_xor(s[r], 1);
            s[r] += __shfl_xor(s[r], 2);
            s[r] += __shfl_xor(s[r], 4);
            s[r] += __shfl_xor(s[r], 8);
        }
        if (l16 == 0) {
#pragma unroll
            for (int r = 0; r < 4; r++) {
                int mg = m0 + wm + i * 16 + quad * 4 + r;
                atomicAdd(&scores[mg], s[r]);
            }
        }
    }
}

// ---------------- fused softmax + context ----------------
// 512 blocks = 16 b x 32 s-chunks of 64 rows. Each block redundantly computes
// its batch's softmax stats from the 2048 scores (8 KB, L2-hot), writes its own
// 64-element weights slice, then accumulates its context partial via atomics.
__global__ __launch_bounds__(256) void softmax_context_kernel(
    const float* __restrict__ A, const float* __restrict__ scores,
    float* __restrict__ wout, float* __restrict__ ctx)
{
    int b = blockIdx.x >> 5;
    int sc = blockIdx.x & 31;
    int tid = threadIdx.x;
    const float* srow = scores + b * SS;

    // batch max + sumexp (full coverage: 256 thr x 8)
    float x[8];
    float mx = -1e30f;
#pragma unroll
    for (int i = 0; i < 8; i++) { x[i] = srow[tid + i * 256]; mx = fmaxf(mx, x[i]); }
#pragma unroll
    for (int off = 32; off; off >>= 1) mx = fmaxf(mx, __shfl_xor(mx, off));
    __shared__ float redm[4], reds[4];
    if ((tid & 63) == 0) redm[tid >> 6] = mx;
    __syncthreads();
    mx = fmaxf(fmaxf(redm[0], redm[1]), fmaxf(redm[2], redm[3]));
    float sum = 0.f;
#pragma unroll
    for (int i = 0; i < 8; i++) sum += __expf(x[i] - mx);
#pragma unroll
    for (int off = 32; off; off >>= 1) sum += __shfl_xor(sum, off);
    if ((tid & 63) == 0) reds[tid >> 6] = sum;
    __syncthreads();
    float inv = 1.0f / (reds[0] + reds[1] + reds[2] + reds[3]);

    // weights for this 64-row chunk -> LDS + global
    __shared__ float wsm[64];
    if (tid < 64) {
        float wv = __expf(srow[sc * 64 + tid] - mx) * inv;
        wsm[tid] = wv;
        wout[b * SS + sc * 64 + tid] = wv;
    }
    __syncthreads();

    // context partial over 64 rows
    const float* arow = A + ((size_t)b * SS + sc * 64) * HH + tid * 4;
    float4 acc = make_float4(0.f, 0.f, 0.f, 0.f);
#pragma unroll 4
    for (int s = 0; s < 64; s++) {
        float w = wsm[s];
        float4 v = *(const float4*)(arow + (size_t)s * HH);
        acc.x += w * v.x; acc.y += w * v.y; acc.z += w * v.z; acc.w += w * v.w;
    }
    float* o = ctx + b * HH + tid * 4;
    atomicAdd(o + 0, acc.x);
    atomicAdd(o + 1, acc.y);
    atomicAdd(o + 2, acc.z);
    atomicAdd(o + 3, acc.w);
}

extern "C" void kernel_launch(void* const* d_in, const int* in_sizes, int n_in,
                              void* d_out, int out_size, void* d_ws, size_t ws_size,
                              hipStream_t stream) {
    const float* h    = (const float*)d_in[0];
    // d_in[1] = c (unused by reference)
    const float* a    = (const float*)d_in[2];
    const float* W    = (const float*)d_in[3];
    const float* bias = (const float*)d_in[4];
    const float* vW   = (const float*)d_in[5];
    float* out = (float*)d_out;

    float* projh  = (float*)d_ws;              // 16384 f32  (64 KB)
    float* scores = projh + BB * HH;           // 32768 f32  (128 KB)
    __bf16* Wb = (__bf16*)(scores + MM);       // 1M bf16    (2 MB)
    __bf16* Ab = Wb + (size_t)HH * HH;         // 33.5M bf16 (67.1 MB)
    const size_t need = (size_t)(BB * HH + MM) * 4 + (size_t)HH * HH * 2
                      + (size_t)MM * HH * 2;

    if (ws_size >= need) {
        prep_all_kernel<<<336 + MM * HH / 8 / 256, 256, 0, stream>>>(
            h, W, bias, a, projh, Wb, Ab, scores, out);
        gemm_scores_kernel<<<512, 512, 0, stream>>>(Ab, Wb, projh, vW, scores);
    } else {
        prep_all_kernel<<<336, 256, 0, stream>>>(h, W, bias, a, projh, Wb, Ab, scores, out);
        gemm_scores_f32_kernel<<<dim3(HH / 128, MM / 128), 256, 0, stream>>>(a, W, projh, vW, scores);
    }

    softmax_context_kernel<<<BB * 32, 256, 0, stream>>>(a, scores, out + BB * HH, out);
}

// Round 7
// 294.816 us; speedup vs baseline: 1.7172x; 1.0007x over previous
//
#include <hip/hip_runtime.h>
#include <hip/hip_bf16.h>

// Problem: B=16, S=2048, H=1024
//   a = encoder_outputs (B,S,H) f32
//   projh[b,o] = sum_h h[b,h]*W[o,h] + bias[o]
//   scores[b,s] = sum_o relu( sum_h a[b,s,h]*W[o,H+h] + projh[b,o] ) * v[o]
//   weights = softmax_s(scores); context[b,h] = sum_s weights[b,s]*a[b,s,h]
// Outputs concat: context (16*1024 f32) then weights (16*2048 f32)
//
// 3 dispatches: prep_all -> gemm (writes 4 score partial slices, no atomics)
//            -> softmax_context (sums partials, softmax, context from bf16 A).
// Note: harness ws_size = 512 MB (observed via 512 MB poison fill each iter);
// its fill (~78 us) + d_in restore are fixed overhead outside our control.

typedef __bf16 bf16x8 __attribute__((ext_vector_type(8)));
typedef float floatx4 __attribute__((ext_vector_type(4)));

#define BB 16
#define SS 2048
#define HH 1024
#define MM (BB * SS)

#define GLB(p) ((const __attribute__((address_space(1))) void*)(p))
#define LDSP(p) ((__attribute__((address_space(3))) void*)(p))

__device__ inline ushort f2bf(float x) {
    uint32_t u = __builtin_bit_cast(uint32_t, x);
    u += 0x7FFFu + ((u >> 16) & 1u);   // round-to-nearest-even
    return (ushort)(u >> 16);
}

// ---------------- prep_all ----------------
// bids [0,256): projh; [256,320): convert_W; [320,336): zero sp0+ctx;
// [336,16720): convert_A (f32 -> bf16, 33.5M elems).
__global__ __launch_bounds__(256) void prep_all_kernel(
    const float* __restrict__ h, const float* __restrict__ W,
    const float* __restrict__ bias, const float* __restrict__ a,
    float* __restrict__ projh, __bf16* __restrict__ Wb, __bf16* __restrict__ Ab,
    float* __restrict__ sp0, float* __restrict__ ctx)
{
    int bid = blockIdx.x;
    int tid = threadIdx.x;
    if (bid >= 336) {
        size_t i = (size_t)(bid - 336) * 256 + tid;   // 8-elem group
        const float* s = a + i * 8;
        float4 x = *(const float4*)(s);
        float4 y = *(const float4*)(s + 4);
        union { ushort u[8]; uint4 v; } p;
        p.u[0] = f2bf(x.x); p.u[1] = f2bf(x.y); p.u[2] = f2bf(x.z); p.u[3] = f2bf(x.w);
        p.u[4] = f2bf(y.x); p.u[5] = f2bf(y.y); p.u[6] = f2bf(y.z); p.u[7] = f2bf(y.w);
        *(uint4*)(Ab + i * 8) = p.v;
    } else if (bid < 256) {
        // projh: (16,1024) = h(16,1024) x W[:, :H]^T + bias
        int b = bid >> 4;
        int oc = bid & 15;
        __shared__ float hrow[HH];
        *(float4*)&hrow[tid * 4] = *(const float4*)(h + (size_t)b * HH + tid * 4);
        __syncthreads();
        int ol = tid >> 2;           // 0..63
        int kq = tid & 3;            // 0..3 (k quarter)
        int o = oc * 64 + ol;
        const float* wr = W + (size_t)o * (2 * HH) + kq * 256;
        const float* hb = hrow + kq * 256;
        float sum = 0.f;
        for (int k = 0; k < 256; k += 4) {
            float4 wv = *(const float4*)(wr + k);
            sum += hb[k] * wv.x + hb[k + 1] * wv.y + hb[k + 2] * wv.z + hb[k + 3] * wv.w;
        }
        sum += __shfl_xor(sum, 1);
        sum += __shfl_xor(sum, 2);
        if (kq == 0) projh[b * HH + o] = sum + bias[o];
    } else if (bid < 320) {
        // convert W[:, H:2H] -> Wb (1024x1024 bf16)
        int cb = bid - 256;
#pragma unroll
        for (int j = 0; j < 8; j++) {
            int g = cb * 2048 + tid + j * 256;
            int o = g >> 7;
            int k = (g & 127) * 8;
            const float* s = W + (size_t)o * (2 * HH) + HH + k;
            float4 x = *(const float4*)(s);
            float4 y = *(const float4*)(s + 4);
            union { ushort u[8]; uint4 v; } p;
            p.u[0] = f2bf(x.x); p.u[1] = f2bf(x.y); p.u[2] = f2bf(x.z); p.u[3] = f2bf(x.w);
            p.u[4] = f2bf(y.x); p.u[5] = f2bf(y.y); p.u[6] = f2bf(y.z); p.u[7] = f2bf(y.w);
            *(uint4*)(Wb + (size_t)o * HH + k) = p.v;
        }
    } else {
        // zero sp0 (32768 f32, fallback path) and ctx (16384 f32): 16 blocks
        int zb = bid - 320;
        float4 z = make_float4(0.f, 0.f, 0.f, 0.f);
        float* sp = sp0 + zb * 2048 + tid * 8;
        *(float4*)(sp) = z;
        *(float4*)(sp + 4) = z;
        *(float4*)(ctx + zb * 1024 + tid * 4) = z;
    }
}

// ---------------- main GEMM: 256x256 tile, 8 waves, BK=32, LDS double-buffer ----------------
// K-loop unchanged from round 5 (78 us, MfmaUtil 36% — the structural plateau).
// Epilogue: LDS-reduce the 4 n-wave partials per m, write scores_part slice
// nq = (bid>>3)&3 — every element written exactly once (no atomics, no zeroing).
__global__ __launch_bounds__(512, 2) void gemm_scores_kernel(
    const __bf16* __restrict__ Ab,    // (32768,1024) bf16
    const __bf16* __restrict__ Wb,    // (1024,1024) bf16 (cols H..2H of W)
    const float* __restrict__ projh,  // (16,1024) f32
    const float* __restrict__ vW,     // (1024) f32
    float* __restrict__ scores_part)  // (4, 32768) f32
{
    __shared__ __bf16 smem[32768];    // 64 KB: 2 bufs x (As 8192 | Bs 8192 elems)

    const int bid = blockIdx.x;
    const int m0 = (((bid >> 5) << 3) + (bid & 7)) * 256;  // 128 M-tiles
    const int nq = (bid >> 3) & 3;
    const int n0 = nq * 256;                               // 4 N-tiles
    const int bidx = m0 >> 11;        // batch index (256 divides 2048)

    const int tid = threadIdx.x;
    const int lane = tid & 63;
    const int wave = tid >> 6;        // 0..7
    const int wm = (wave & 1) * 128;  // wave tile: 128 (M) x 64 (N)
    const int wn = (wave >> 1) * 64;
    const int quad = lane >> 4;
    const int l16 = lane & 15;

    floatx4 acc[8][4];
    const floatx4 z = {0.f, 0.f, 0.f, 0.f};
#pragma unroll
    for (int i = 0; i < 8; i++)
#pragma unroll
        for (int j = 0; j < 4; j++) acc[i][j] = z;

    const int su = tid >> 3;
    const int sj = (tid & 7) ^ (su & 7);
    const int g_row = su * 2 + (sj >> 2);
    const int g_col = (sj & 3) * 8;
    const __bf16* gA  = Ab + (size_t)(m0 + g_row) * HH + g_col;
    const __bf16* gA2 = gA + (size_t)128 * HH;
    const __bf16* gB  = Wb + (size_t)(n0 + g_row) * HH + g_col;
    const __bf16* gB2 = gB + (size_t)128 * HH;
    const int ldsb = wave * 512;      // wave-uniform chunk base (elems)

    int aoff[8], boff[4];
#pragma unroll
    for (int i = 0; i < 8; i++) {
        int frow = wm + i * 16 + l16;
        int u2 = frow >> 1;
        int cc = u2 * 8 + (((((frow & 1) << 2) | quad)) ^ (u2 & 7));
        aoff[i] = cc * 8;
    }
#pragma unroll
    for (int j = 0; j < 4; j++) {
        int frow = wn + j * 16 + l16;
        int u2 = frow >> 1;
        int cc = u2 * 8 + (((((frow & 1) << 2) | quad)) ^ (u2 & 7));
        boff[j] = 8192 + cc * 8;
    }

#define ISSUE_STAGE(buf, k0)                                                          \
    {                                                                                 \
        __bf16* dst = smem + (buf) * 16384 + ldsb;                                    \
        __builtin_amdgcn_global_load_lds(GLB(gA  + (k0)), LDSP(dst),         16, 0, 0); \
        __builtin_amdgcn_global_load_lds(GLB(gA2 + (k0)), LDSP(dst + 4096),  16, 0, 0); \
        __builtin_amdgcn_global_load_lds(GLB(gB  + (k0)), LDSP(dst + 8192),  16, 0, 0); \
        __builtin_amdgcn_global_load_lds(GLB(gB2 + (k0)), LDSP(dst + 12288), 16, 0, 0); \
    }

    ISSUE_STAGE(0, 0)
    for (int s = 0; s < 32; s++) {
        __syncthreads();   // drains buf[s&1] loads (issued a full stage ago)
        if (s < 31) ISSUE_STAGE((s + 1) & 1, (s + 1) * 32)
        const __bf16* sb = smem + (s & 1) * 16384;
        bf16x8 af[8], bfr[4];
#pragma unroll
        for (int j = 0; j < 4; j++) bfr[j] = *(const bf16x8*)(sb + boff[j]);
#pragma unroll
        for (int i = 0; i < 8; i++) af[i] = *(const bf16x8*)(sb + aoff[i]);
#pragma unroll
        for (int i = 0; i < 8; i++)
#pragma unroll
            for (int j = 0; j < 4; j++)
                acc[i][j] = __builtin_amdgcn_mfma_f32_16x16x32_bf16(af[i], bfr[j], acc[i][j], 0, 0, 0);
    }
#undef ISSUE_STAGE

    // epilogue: partial[m] = sum over this block's 256 n of relu(acc + projh)*v
    float ph[4], vv[4];
#pragma unroll
    for (int j = 0; j < 4; j++) {
        int ng = n0 + wn + j * 16 + l16;
        ph[j] = projh[bidx * HH + ng];
        vv[j] = vW[ng];
    }

    // LDS cross-wave reduction buffer (reuses buf0 region; all waves are past
    // the final top-of-loop barrier, after which only buf1 is read).
    float* red = (float*)smem;
    if (tid < 256) red[tid] = 0.f;
    __syncthreads();

#pragma unroll
    for (int i = 0; i < 8; i++) {
        float s[4] = {0.f, 0.f, 0.f, 0.f};
#pragma unroll
        for (int j = 0; j < 4; j++) {
#pragma unroll
            for (int r2 = 0; r2 < 4; r2++) {
                float e = acc[i][j][r2] + ph[j];
                e = e > 0.f ? e : 0.f;
                s[r2] += e * vv[j];
            }
        }
#pragma unroll
        for (int r2 = 0; r2 < 4; r2++) {
            s[r2] += __shfl_xor(s[r2], 1);
            s[r2] += __shfl_xor(s[r2], 2);
            s[r2] += __shfl_xor(s[r2], 4);
            s[r2] += __shfl_xor(s[r2], 8);
        }
        if (l16 == 0) {
#pragma unroll
            for (int r2 = 0; r2 < 4; r2++)
                atomicAdd(&red[wm + i * 16 + quad * 4 + r2], s[r2]);  // LDS atomic
        }
    }
    __syncthreads();
    if (tid < 256) scores_part[(size_t)nq * MM + m0 + tid] = red[tid];
}

// ---------------- fallback GEMM (f32 staging, atomics into scores_part[0]) ----------------
__global__ __launch_bounds__(256) void gemm_scores_f32_kernel(
    const float* __restrict__ A, const float* __restrict__ W,
    const float* __restrict__ projh, const float* __restrict__ vW,
    float* __restrict__ scores)       // scores_part slice 0, pre-zeroed by prep
{
    constexpr int BM = 128, BN = 128, BK = 32, LDT = BK + 8;
    __shared__ __bf16 As[BM * LDT];
    __shared__ __bf16 Bs[BN * LDT];
    const int n0 = blockIdx.x * BN;
    const int m0 = blockIdx.y * BM;
    const int bidx = m0 >> 11;
    const int tid = threadIdx.x;
    const int lane = tid & 63;
    const int wave = tid >> 6;
    const int wm = (wave & 1) * 64;
    const int wn = (wave >> 1) * 64;
    const int quad = lane >> 4;
    const int l16 = lane & 15;
    floatx4 acc[4][4];
    const floatx4 z = {0.f, 0.f, 0.f, 0.f};
#pragma unroll
    for (int i = 0; i < 4; i++)
#pragma unroll
        for (int j = 0; j < 4; j++) acc[i][j] = z;
    int rowT[4], colT[4];
#pragma unroll
    for (int i = 0; i < 4; i++) {
        int fi = tid + 256 * i;
        rowT[i] = fi >> 3;
        colT[i] = (fi & 7) * 4;
    }
    for (int k0 = 0; k0 < HH; k0 += BK) {
        float4 av[4], bv[4];
#pragma unroll
        for (int i = 0; i < 4; i++) {
            av[i] = *(const float4*)(A + (size_t)(m0 + rowT[i]) * HH + k0 + colT[i]);
            bv[i] = *(const float4*)(W + (size_t)(n0 + rowT[i]) * (2 * HH) + HH + k0 + colT[i]);
        }
        __syncthreads();
#pragma unroll
        for (int i = 0; i < 4; i++) {
            ushort4 ua = make_ushort4(f2bf(av[i].x), f2bf(av[i].y), f2bf(av[i].z), f2bf(av[i].w));
            ushort4 ub = make_ushort4(f2bf(bv[i].x), f2bf(bv[i].y), f2bf(bv[i].z), f2bf(bv[i].w));
            *(ushort4*)&As[rowT[i] * LDT + colT[i]] = ua;
            *(ushort4*)&Bs[rowT[i] * LDT + colT[i]] = ub;
        }
        __syncthreads();
        bf16x8 af[4], bf[4];
#pragma unroll
        for (int i = 0; i < 4; i++)
            af[i] = *(const bf16x8*)&As[(wm + i * 16 + l16) * LDT + quad * 8];
#pragma unroll
        for (int j = 0; j < 4; j++)
            bf[j] = *(const bf16x8*)&Bs[(wn + j * 16 + l16) * LDT + quad * 8];
#pragma unroll
        for (int i = 0; i < 4; i++)
#pragma unroll
            for (int j = 0; j < 4; j++)
                acc[i][j] = __builtin_amdgcn_mfma_f32_16x16x32_bf16(af[i], bf[j], acc[i][j], 0, 0, 0);
    }
    float ph[4], vv[4];
#pragma unroll
    for (int j = 0; j < 4; j++) {
        int ng = n0 + wn + j * 16 + l16;
        ph[j] = projh[bidx * HH + ng];
        vv[j] = vW[ng];
    }
#pragma unroll
    for (int i = 0; i < 4; i++) {
        float s[4] = {0.f, 0.f, 0.f, 0.f};
#pragma unroll
        for (int j = 0; j < 4; j++) {
#pragma unroll
            for (int r = 0; r < 4; r++) {
                float e = acc[i][j][r] + ph[j];
                e = e > 0.f ? e : 0.f;
                s[r] += e * vv[j];
            }
        }
#pragma unroll
        for (int r = 0; r < 4; r++) {
            s[r] += __shfl_xor(s[r], 1);
            s[r] += __shfl_xor(s[r], 2);
            s[r] += __shfl_xor(s[r], 4);
            s[r] += __shfl_xor(s[r], 8);
        }
        if (l16 == 0) {
#pragma unroll
            for (int r = 0; r < 4; r++) {
                int mg = m0 + wm + i * 16 + quad * 4 + r;
                atomicAdd(&scores[mg], s[r]);
            }
        }
    }
}

// ---------------- fused softmax + context (context reads bf16 Ab) ----------------
// 512 blocks = 16 b x 32 s-chunks of 64 rows. Each block sums nparts score
// partials, computes its batch's softmax stats (redundant, L2-hot), writes its
// 64-element weights slice, then accumulates context partials via atomics.
__global__ __launch_bounds__(256) void softmax_context_kernel(
    const __bf16* __restrict__ Ab, const float* __restrict__ scores_part,
    int nparts, float* __restrict__ wout, float* __restrict__ ctx)
{
    int b = blockIdx.x >> 5;
    int sc = blockIdx.x & 31;
    int tid = threadIdx.x;
    const float* srow = scores_part + b * SS;

    // batch scores = sum of partials; max + sumexp (256 thr x 8 covers S=2048)
    float x[8];
    float mx = -1e30f;
#pragma unroll
    for (int i = 0; i < 8; i++) {
        int idx = tid + i * 256;
        float v = srow[idx];
        for (int q = 1; q < nparts; q++) v += srow[(size_t)q * MM + idx];
        x[i] = v; mx = fmaxf(mx, v);
    }
#pragma unroll
    for (int off = 32; off; off >>= 1) mx = fmaxf(mx, __shfl_xor(mx, off));
    __shared__ float redm[4], reds[4];
    if ((tid & 63) == 0) redm[tid >> 6] = mx;
    __syncthreads();
    mx = fmaxf(fmaxf(redm[0], redm[1]), fmaxf(redm[2], redm[3]));
    float sum = 0.f;
#pragma unroll
    for (int i = 0; i < 8; i++) sum += __expf(x[i] - mx);
#pragma unroll
    for (int off = 32; off; off >>= 1) sum += __shfl_xor(sum, off);
    if ((tid & 63) == 0) reds[tid >> 6] = sum;
    __syncthreads();
    float inv = 1.0f / (reds[0] + reds[1] + reds[2] + reds[3]);

    // weights for this 64-row chunk -> LDS + global
    __shared__ float wsm[64];
    if (tid < 64) {
        int idx = sc * 64 + tid;
        float v = srow[idx];
        for (int q = 1; q < nparts; q++) v += srow[(size_t)q * MM + idx];
        float wv = __expf(v - mx) * inv;
        wsm[tid] = wv;
        wout[b * SS + idx] = wv;
    }
    __syncthreads();

    // context partial over 64 rows, bf16 A (4 cols per thread)
    const __bf16* arow = Ab + ((size_t)b * SS + sc * 64) * HH + tid * 4;
    float4 acc = make_float4(0.f, 0.f, 0.f, 0.f);
#pragma unroll 4
    for (int s = 0; s < 64; s++) {
        float w = wsm[s];
        uint2 uv = *(const uint2*)(arow + (size_t)s * HH);
        float a0 = __builtin_bit_cast(float, uv.x << 16);
        float a1 = __builtin_bit_cast(float, uv.x & 0xffff0000u);
        float a2 = __builtin_bit_cast(float, uv.y << 16);
        float a3 = __builtin_bit_cast(float, uv.y & 0xffff0000u);
        acc.x += w * a0; acc.y += w * a1; acc.z += w * a2; acc.w += w * a3;
    }
    float* o = ctx + b * HH + tid * 4;
    atomicAdd(o + 0, acc.x);
    atomicAdd(o + 1, acc.y);
    atomicAdd(o + 2, acc.z);
    atomicAdd(o + 3, acc.w);
}

// f32-A variant for the fallback path (no Ab available)
__global__ __launch_bounds__(256) void softmax_context_f32_kernel(
    const float* __restrict__ A, const float* __restrict__ scores_part,
    float* __restrict__ wout, float* __restrict__ ctx)
{
    int b = blockIdx.x >> 5;
    int sc = blockIdx.x & 31;
    int tid = threadIdx.x;
    const float* srow = scores_part + b * SS;
    float x[8];
    float mx = -1e30f;
#pragma unroll
    for (int i = 0; i < 8; i++) { x[i] = srow[tid + i * 256]; mx = fmaxf(mx, x[i]); }
#pragma unroll
    for (int off = 32; off; off >>= 1) mx = fmaxf(mx, __shfl_xor(mx, off));
    __shared__ float redm[4], reds[4];
    if ((tid & 63) == 0) redm[tid >> 6] = mx;
    __syncthreads();
    mx = fmaxf(fmaxf(redm[0], redm[1]), fmaxf(redm[2], redm[3]));
    float sum = 0.f;
#pragma unroll
    for (int i = 0; i < 8; i++) sum += __expf(x[i] - mx);
#pragma unroll
    for (int off = 32; off; off >>= 1) sum += __shfl_xor(sum, off);
    if ((tid & 63) == 0) reds[tid >> 6] = sum;
    __syncthreads();
    float inv = 1.0f / (reds[0] + reds[1] + reds[2] + reds[3]);
    __shared__ float wsm[64];
    if (tid < 64) {
        float wv = __expf(srow[sc * 64 + tid] - mx) * inv;
        wsm[tid] = wv;
        wout[b * SS + sc * 64 + tid] = wv;
    }
    __syncthreads();
    const float* arow = A + ((size_t)b * SS + sc * 64) * HH + tid * 4;
    float4 acc = make_float4(0.f, 0.f, 0.f, 0.f);
#pragma unroll 4
    for (int s = 0; s < 64; s++) {
        float w = wsm[s];
        float4 v = *(const float4*)(arow + (size_t)s * HH);
        acc.x += w * v.x; acc.y += w * v.y; acc.z += w * v.z; acc.w += w * v.w;
    }
    float* o = ctx + b * HH + tid * 4;
    atomicAdd(o + 0, acc.x);
    atomicAdd(o + 1, acc.y);
    atomicAdd(o + 2, acc.z);
    atomicAdd(o + 3, acc.w);
}

extern "C" void kernel_launch(void* const* d_in, const int* in_sizes, int n_in,
                              void* d_out, int out_size, void* d_ws, size_t ws_size,
                              hipStream_t stream) {
    const float* h    = (const float*)d_in[0];
    // d_in[1] = c (unused by reference)
    const float* a    = (const float*)d_in[2];
    const float* W    = (const float*)d_in[3];
    const float* bias = (const float*)d_in[4];
    const float* vW   = (const float*)d_in[5];
    float* out = (float*)d_out;

    float* projh       = (float*)d_ws;             // 16384 f32   (64 KB)
    float* scores_part = projh + BB * HH;          // 4*32768 f32 (512 KB)
    __bf16* Wb = (__bf16*)(scores_part + 4 * MM);  // 1M bf16     (2 MB)
    __bf16* Ab = Wb + (size_t)HH * HH;             // 33.5M bf16  (67.1 MB)
    const size_t need = (size_t)(BB * HH + 4 * MM) * 4 + (size_t)HH * HH * 2
                      + (size_t)MM * HH * 2;

    if (ws_size >= need) {
        prep_all_kernel<<<336 + MM * HH / 8 / 256, 256, 0, stream>>>(
            h, W, bias, a, projh, Wb, Ab, scores_part, out);
        gemm_scores_kernel<<<512, 512, 0, stream>>>(Ab, Wb, projh, vW, scores_part);
        softmax_context_kernel<<<BB * 32, 256, 0, stream>>>(
            Ab, scores_part, 4, out + BB * HH, out);
    } else {
        prep_all_kernel<<<336, 256, 0, stream>>>(h, W, bias, a, projh, Wb, Ab, scores_part, out);
        gemm_scores_f32_kernel<<<dim3(HH / 128, MM / 128), 256, 0, stream>>>(
            a, W, projh, vW, scores_part);
        softmax_context_f32_kernel<<<BB * 32, 256, 0, stream>>>(
            a, scores_part, out + BB * HH, out);
    }
}